// Round 5
// baseline (780.921 us; speedup 1.0000x reference)
//
#include <hip/hip_runtime.h>
#include <stdint.h>

// Experts MLP: out[b,e] = gelu(x[b,e] @ w1[e] + b1[e]) @ w2[e] + b2[e]
// B=4 E=8 N=1024 D=1024 H=4096.
// Round 5: pipelined 4-barrier K-tile: each region holds {MFMA(i) || ds_read(i+1)
// || stage issue}; vmcnt(2) before the ph2-end barrier (cross-wave safe); frag
// reads placed after their consumers so compiler may overlap via renaming.

typedef __attribute__((ext_vector_type(8))) short short8;
typedef __attribute__((ext_vector_type(4))) float f32x4;

__device__ __forceinline__ unsigned short f2b(float f){
  union { float f; unsigned int u; } v; v.f = f;
  unsigned int r = v.u + 0x7fffu + ((v.u >> 16) & 1u);   // RNE
  return (unsigned short)(r >> 16);
}

// tanh-form GELU via exp2/rcp (verified r3/r4)
__device__ __forceinline__ float gelu_fast(float v){
  float v2 = v * v;
  float w = v * (-2.302217529693f + -0.102943795894f * v2);
  float e = __builtin_amdgcn_exp2f(w);
  return v * __builtin_amdgcn_rcpf(1.0f + e);
}

__device__ __forceinline__ void glds16(const void* g, const void* l){
  __builtin_amdgcn_global_load_lds((const __attribute__((address_space(1))) uint32_t*)g,
                                   (__attribute__((address_space(3))) uint32_t*)l, 16, 0, 0);
}

#define BAR() do{ asm volatile("" ::: "memory"); __builtin_amdgcn_s_barrier(); asm volatile("" ::: "memory"); }while(0)

// ---------------- prep kernels (verified r1-r4) ----------------

__global__ void cvt_x_kernel(const float* __restrict__ src, unsigned short* __restrict__ dst, int n4){
  int i = blockIdx.x * blockDim.x + threadIdx.x;
  int stride = gridDim.x * blockDim.x;
  for (; i < n4; i += stride){
    float4 v = ((const float4*)src)[i];
    ushort4 o;
    o.x = f2b(v.x); o.y = f2b(v.y); o.z = f2b(v.z); o.w = f2b(v.w);
    ((ushort4*)dst)[i] = o;
  }
}

__global__ void transpose_cvt(const float* __restrict__ src, unsigned short* __restrict__ dst, int R, int C){
  __shared__ float t[64][65];
  const int e = blockIdx.z;
  src += (size_t)e * R * C;
  dst += (size_t)e * R * C;
  const int r0 = blockIdx.y * 64, c0 = blockIdx.x * 64;
  const int tid = threadIdx.x;
  const int lr = tid >> 4;
  const int lc4 = (tid & 15) * 4;
  #pragma unroll
  for (int p2 = 0; p2 < 4; p2++){
    int r = lr + p2 * 16;
    float4 v = *(const float4*)(src + (size_t)(r0 + r) * C + (c0 + lc4));
    t[r][lc4+0] = v.x; t[r][lc4+1] = v.y; t[r][lc4+2] = v.z; t[r][lc4+3] = v.w;
  }
  __syncthreads();
  #pragma unroll
  for (int p2 = 0; p2 < 4; p2++){
    int c = lr + p2 * 16;
    ushort4 o;
    o.x = f2b(t[lc4+0][c]); o.y = f2b(t[lc4+1][c]);
    o.z = f2b(t[lc4+2][c]); o.w = f2b(t[lc4+3][c]);
    *(ushort4*)(dst + (size_t)(c0 + c) * R + (r0 + lc4)) = o;
  }
}

// ---------------- 256x256 pipelined GEMM ----------------
// LDS rows = 64 bf16 (8 x 16B chunks); chunk c of row r at LDS chunk
// (c ^ (r&7)); LDS linear + pre-swizzled global source (rule #21).
// LDS map (shorts): A buf0 @0, A buf1 @16384, B buf0 @32768, B buf1 @49152.
// A-frag halves: afL = rows {0-63,128-191} (blocks pA0,pA2),
//                afH = rows {64-127,192-255} (blocks pA1,pA3).

template<int PHASE1>
__global__ __launch_bounds__(512, 2) void gemm256(
    const unsigned short* __restrict__ A,
    const unsigned short* __restrict__ Bt,
    const float* __restrict__ bias,
    void* __restrict__ Out,
    int p0)
{
  constexpr int M  = 1024;
  constexpr int K  = PHASE1 ? 1024 : 4096;
  constexpr int Nd = PHASE1 ? 4096 : 1024;
  constexpr int TM = M / 256, TN = Nd / 256;
  constexpr int NT = K / 64;                 // 16 or 64 (even, >=4)

  const int cpx = gridDim.x >> 3;
  const int bid = (blockIdx.x & 7) * cpx + (blockIdx.x >> 3);
  const int tn = bid % TN;
  const int t2 = bid / TN;
  const int tm = t2 % TM;
  const int cp = t2 / TM;
  const int p  = p0 + cp, e = p & 7;
  const int m0 = tm * 256, n0 = tn * 256;

  const unsigned short* Ag = A  + (size_t)(PHASE1 ? p : cp) * M * K + (size_t)m0 * K;
  const unsigned short* Bg = Bt + (size_t)e * Nd * K + (size_t)n0 * K;
  const float*          bp = bias + (size_t)e * Nd;

  __shared__ __align__(16) unsigned short lds[65536];

  const int tid = threadIdx.x;
  const int w = tid >> 6, lane = tid & 63;
  const int wr = w >> 2, wc = w & 3;          // 2 x 4 waves; wave tile 128 x 64
  const int c15 = lane & 15, q = lane >> 4;

  // staging addresses
  const int trow = (w << 3) + (lane >> 3);                 // 0..63
  const int scol = ((lane & 7) ^ (trow & 7)) << 3;
  const unsigned short* pA0 = Ag + (size_t)(trow       ) * K + scol;
  const unsigned short* pA1 = Ag + (size_t)(trow +  64) * K + scol;
  const unsigned short* pA2 = Ag + (size_t)(trow + 128) * K + scol;
  const unsigned short* pA3 = Ag + (size_t)(trow + 192) * K + scol;
  const unsigned short* pB0 = Bg + (size_t)(trow       ) * K + scol;
  const unsigned short* pB1 = Bg + (size_t)(trow +  64) * K + scol;
  const unsigned short* pB2 = Bg + (size_t)(trow + 128) * K + scol;
  const unsigned short* pB3 = Bg + (size_t)(trow + 192) * K + scol;
  const int wof = w << 9;                                  // LDS dest base (shorts)

  // frag-read per-thread constants (shorts)
  const int rA64 = (wr * 128 + c15) << 6;
  const int rB64 = (wc * 64  + c15) << 6;
  const int cx0 = ( q      ^ (c15 & 7)) << 3;
  const int cx1 = ((q ^ 4) ^ (c15 & 7)) << 3;

  float bv[4];
  #pragma unroll
  for (int nf = 0; nf < 4; ++nf) bv[nf] = bp[n0 + wc * 64 + nf * 16 + c15];

  f32x4 acc[8][4];
  #pragma unroll
  for (int i = 0; i < 8; i++)
    #pragma unroll
    for (int j = 0; j < 4; j++) acc[i][j] = (f32x4)(bv[j]);

  short8 afA[2][2], afB[2][2], bf0_[2][2], bf1_[2][2];

#define LD(OFS) (*(const short8*)(lds + (OFS)))
#define RD_AFA(BASE) do{ _Pragma("unroll") for (int mi=0;mi<2;++mi){ \
    afA[mi][0] = LD((BASE) + rA64 + mi*1024 + cx0); \
    afA[mi][1] = LD((BASE) + rA64 + mi*1024 + cx1); } }while(0)
#define RD_AFB(BASE) do{ _Pragma("unroll") for (int mi=0;mi<2;++mi){ \
    afB[mi][0] = LD((BASE) + rA64 + 2048 + mi*1024 + cx0); \
    afB[mi][1] = LD((BASE) + rA64 + 2048 + mi*1024 + cx1); } }while(0)
#define RD_BF0(BASE) do{ _Pragma("unroll") for (int nf=0;nf<2;++nf){ \
    bf0_[nf][0] = LD((BASE) + rB64 + nf*1024 + cx0); \
    bf0_[nf][1] = LD((BASE) + rB64 + nf*1024 + cx1); } }while(0)
#define RD_BF1(BASE) do{ _Pragma("unroll") for (int nf=0;nf<2;++nf){ \
    bf1_[nf][0] = LD((BASE) + rB64 + 2048 + nf*1024 + cx0); \
    bf1_[nf][1] = LD((BASE) + rB64 + 2048 + nf*1024 + cx1); } }while(0)
#define Q8(MO,NO,AF,BF) do{ _Pragma("unroll") for (int mi=0;mi<2;++mi) \
    _Pragma("unroll") for (int nf=0;nf<2;++nf){ \
      acc[(MO)+mi][(NO)+nf] = __builtin_amdgcn_mfma_f32_16x16x32_bf16(AF[mi][0], BF[nf][0], acc[(MO)+mi][(NO)+nf],0,0,0); \
      acc[(MO)+mi][(NO)+nf] = __builtin_amdgcn_mfma_f32_16x16x32_bf16(AF[mi][1], BF[nf][1], acc[(MO)+mi][(NO)+nf],0,0,0); } }while(0)

  // ---- prologue: tile0 (A,B) + A_lo(tile1); vmcnt(2); preload afL/bf0(tile0) ----
  glds16(pA0, lds + wof);
  glds16(pA1, lds + wof + 4096);
  glds16(pA2, lds + wof + 8192);
  glds16(pA3, lds + wof + 12288);
  glds16(pB0, lds + wof + 32768);
  glds16(pB1, lds + wof + 32768 + 4096);
  glds16(pB2, lds + wof + 32768 + 8192);
  glds16(pB3, lds + wof + 32768 + 12288);
  glds16(pA0 + 64, lds + wof + 16384);            // A_lo(1): rows 0-63
  glds16(pA2 + 64, lds + wof + 16384 + 8192);     // A_lo(1): rows 128-191
  asm volatile("s_waitcnt vmcnt(2)" ::: "memory");
  BAR();
  RD_AFA(0); RD_AFB(0); RD_BF0(32768);

  // One K-tile. CB = buffer parity; PF1 = next tile exists; PF2 = kt+2 exists.
#define TILE_P(CB, PF1, PF2) do{                                                \
    constexpr int AB  = (CB) * 16384;                                           \
    constexpr int BB  = 32768 + (CB) * 16384;                                   \
    constexpr int ABn = ((CB) ^ 1) * 16384;                                     \
    constexpr int BBn = 32768 + (((CB) ^ 1) * 16384);                           \
    constexpr int O1  = (CB) ? 128 : 64;                                        \
    constexpr int O2  = (CB) ? 192 : 128;                                       \
    /* ph0: q00 = afL x bf0 ; read bf1 ; stage A_hi(kt+1) */                    \
    RD_BF1(BB);                                                                 \
    if (PF1){ glds16(pA1 + O1, lds + ABn + 4096 + wof);                         \
              glds16(pA3 + O1, lds + ABn + 12288 + wof); }                      \
    __builtin_amdgcn_s_setprio(1);                                              \
    Q8(0,0,afA,bf0_); Q8(2,0,afB,bf0_);                                         \
    __builtin_amdgcn_s_setprio(0);                                              \
    BAR();                                                                      \
    /* ph1: q01 = afL x bf1 ; stage B(kt+1) ; then reload afA <- afH[0:1] */    \
    if (PF1){ glds16(pB0 + O1, lds + BBn + wof);                                \
              glds16(pB1 + O1, lds + BBn + 4096 + wof);                         \
              glds16(pB2 + O1, lds + BBn + 8192 + wof);                         \
              glds16(pB3 + O1, lds + BBn + 12288 + wof); }                      \
    __builtin_amdgcn_s_setprio(1);                                              \
    Q8(0,2,afA,bf1_); Q8(2,2,afB,bf1_);                                         \
    __builtin_amdgcn_s_setprio(0);                                              \
    RD_AFA(AB + 4096);                                                          \
    BAR();                                                                      \
    /* ph2: q11 = afH x bf1 ; read afB <- afH[2:3] ; stage A_lo(kt+2) ; vmcnt */\
    RD_AFB(AB + 4096);                                                          \
    if (PF2){ glds16(pA0 + O2, lds + AB + wof);                                 \
              glds16(pA2 + O2, lds + AB + 8192 + wof); }                        \
    __builtin_amdgcn_s_setprio(1);                                              \
    Q8(4,2,afA,bf1_); Q8(6,2,afB,bf1_);                                         \
    __builtin_amdgcn_s_setprio(0);                                              \
    if (PF1){ if (PF2){ asm volatile("s_waitcnt vmcnt(2)" ::: "memory"); }      \
              else    { asm volatile("s_waitcnt vmcnt(0)" ::: "memory"); } }    \
    BAR();                                                                      \
    /* ph3: q10 = afH x bf0 ; then prefetch next tile's afL + bf0 */            \
    __builtin_amdgcn_s_setprio(1);                                              \
    Q8(4,0,afA,bf0_); Q8(6,0,afB,bf0_);                                         \
    __builtin_amdgcn_s_setprio(0);                                              \
    if (PF1){ RD_AFA(ABn); RD_AFB(ABn); RD_BF0(BBn); }                          \
    BAR();                                                                      \
  }while(0)

  for (int kt2 = 0; kt2 < NT - 2; kt2 += 2){
    TILE_P(0, 1, 1);
    TILE_P(1, 1, 1);
    pA0 += 128; pA1 += 128; pA2 += 128; pA3 += 128;
    pB0 += 128; pB1 += 128; pB2 += 128; pB3 += 128;
  }
  TILE_P(0, 1, 0);    // kt = NT-2: stage NT-1, drain, prefetch its frags
  TILE_P(1, 0, 0);    // kt = NT-1: compute only
#undef TILE_P

  // ---- epilogue: C/D layout col = lane&15, row = (lane>>4)*4 + r ----
  #pragma unroll
  for (int mf = 0; mf < 8; ++mf){
    const int row = m0 + wr * 128 + mf * 16 + q * 4;
    #pragma unroll
    for (int nf = 0; nf < 4; ++nf){
      const int col = n0 + wc * 64 + nf * 16 + c15;
      #pragma unroll
      for (int r = 0; r < 4; ++r){
        float v = acc[mf][nf][r];
        if constexpr (PHASE1){
          ((unsigned short*)Out)[(size_t)cp * M * Nd + (size_t)(row + r) * Nd + col] = f2b(gelu_fast(v));
        } else {
          ((float*)Out)[(size_t)p * M * Nd + (size_t)(row + r) * Nd + col] = v;
        }
      }
    }
  }
}

// ---------------- launch ----------------

extern "C" void kernel_launch(void* const* d_in, const int* in_sizes, int n_in,
                              void* d_out, int out_size, void* d_ws, size_t ws_size,
                              hipStream_t stream){
  const float* x  = (const float*)d_in[0];
  const float* w1 = (const float*)d_in[1];
  const float* b1 = (const float*)d_in[2];
  const float* w2 = (const float*)d_in[3];
  const float* b2 = (const float*)d_in[4];
  float* out = (float*)d_out;

  unsigned short* xb  = (unsigned short*)d_ws;
  unsigned short* w1t = (unsigned short*)((char*)d_ws + ((size_t)64  << 20));
  unsigned short* w2t = (unsigned short*)((char*)d_ws + ((size_t)128 << 20));
  unsigned short* hb  = (unsigned short*)((char*)d_ws + ((size_t)192 << 20));

  size_t avail = ws_size > ((size_t)192 << 20) ? ws_size - ((size_t)192 << 20) : 0;
  int ppc = (int)(avail / ((size_t)8 << 20));
  if (ppc > 32) ppc = 32;
  if (ppc < 1) return;

  cvt_x_kernel<<<2048, 256, 0, stream>>>(x, xb, 8 * 1024 * 1024);
  transpose_cvt<<<dim3(64, 16, 8), 256, 0, stream>>>(w1, w1t, 1024, 4096);
  transpose_cvt<<<dim3(16, 64, 8), 256, 0, stream>>>(w2, w2t, 4096, 1024);

  for (int p0 = 0; p0 < 32; p0 += ppc){
    int np = (32 - p0 < ppc) ? (32 - p0) : ppc;
    // GEMM1: h = gelu(xb @ w1t^T + b1)   [M=1024, K=1024, Nd=4096]
    gemm256<1><<<dim3(np * 4 * 16), 512, 0, stream>>>(xb, w1t, b1, hb, p0);
    // GEMM2: out = h @ w2t^T + b2        [M=1024, K=4096, Nd=1024]
    gemm256<0><<<dim3(np * 4 * 4),  512, 0, stream>>>(hb, w2t, b2, out, p0);
  }
}

// Round 6
// 610.831 us; speedup vs baseline: 1.2785x; 1.2785x over previous
//
#include <hip/hip_runtime.h>
#include <stdint.h>

// Experts MLP: out[b,e] = gelu(x[b,e] @ w1[e] + b1[e]) @ w2[e] + b2[e]
// B=4 E=8 N=1024 D=1024 H=4096.
// Round 6: r4's verified 8-barrier 256x256 skeleton, with re-timed staging
// (B early, A-hi late) and loosened counted waits: vmcnt(6) @ ph1-end,
// vmcnt(4) @ ph3-end -> every staged block has >=2.5 phases latency slack
// (m218 counted-vmcnt lever). r5's 4-barrier pipeline REVERTED (regressed).

typedef __attribute__((ext_vector_type(8))) short short8;
typedef __attribute__((ext_vector_type(4))) float f32x4;

__device__ __forceinline__ unsigned short f2b(float f){
  union { float f; unsigned int u; } v; v.f = f;
  unsigned int r = v.u + 0x7fffu + ((v.u >> 16) & 1u);   // RNE
  return (unsigned short)(r >> 16);
}

// tanh-form GELU via exp2/rcp (verified r3-r5)
__device__ __forceinline__ float gelu_fast(float v){
  float v2 = v * v;
  float w = v * (-2.302217529693f + -0.102943795894f * v2);
  float e = __builtin_amdgcn_exp2f(w);
  return v * __builtin_amdgcn_rcpf(1.0f + e);
}

__device__ __forceinline__ void glds16(const void* g, const void* l){
  __builtin_amdgcn_global_load_lds((const __attribute__((address_space(1))) uint32_t*)g,
                                   (__attribute__((address_space(3))) uint32_t*)l, 16, 0, 0);
}

#define BAR() do{ asm volatile("" ::: "memory"); __builtin_amdgcn_s_barrier(); asm volatile("" ::: "memory"); }while(0)
#define VMW(N) do{ if ((N)==6) asm volatile("s_waitcnt vmcnt(6)":::"memory"); \
  else if ((N)==4) asm volatile("s_waitcnt vmcnt(4)":::"memory"); \
  else if ((N)==2) asm volatile("s_waitcnt vmcnt(2)":::"memory"); \
  else if ((N)==0) asm volatile("s_waitcnt vmcnt(0)":::"memory"); }while(0)

// ---------------- prep kernels (verified r1-r5) ----------------

__global__ void cvt_x_kernel(const float* __restrict__ src, unsigned short* __restrict__ dst, int n4){
  int i = blockIdx.x * blockDim.x + threadIdx.x;
  int stride = gridDim.x * blockDim.x;
  for (; i < n4; i += stride){
    float4 v = ((const float4*)src)[i];
    ushort4 o;
    o.x = f2b(v.x); o.y = f2b(v.y); o.z = f2b(v.z); o.w = f2b(v.w);
    ((ushort4*)dst)[i] = o;
  }
}

__global__ void transpose_cvt(const float* __restrict__ src, unsigned short* __restrict__ dst, int R, int C){
  __shared__ float t[64][65];
  const int e = blockIdx.z;
  src += (size_t)e * R * C;
  dst += (size_t)e * R * C;
  const int r0 = blockIdx.y * 64, c0 = blockIdx.x * 64;
  const int tid = threadIdx.x;
  const int lr = tid >> 4;
  const int lc4 = (tid & 15) * 4;
  #pragma unroll
  for (int p2 = 0; p2 < 4; p2++){
    int r = lr + p2 * 16;
    float4 v = *(const float4*)(src + (size_t)(r0 + r) * C + (c0 + lc4));
    t[r][lc4+0] = v.x; t[r][lc4+1] = v.y; t[r][lc4+2] = v.z; t[r][lc4+3] = v.w;
  }
  __syncthreads();
  #pragma unroll
  for (int p2 = 0; p2 < 4; p2++){
    int c = lr + p2 * 16;
    ushort4 o;
    o.x = f2b(t[lc4+0][c]); o.y = f2b(t[lc4+1][c]);
    o.z = f2b(t[lc4+2][c]); o.w = f2b(t[lc4+3][c]);
    *(ushort4*)(dst + (size_t)(c0 + c) * R + (r0 + lc4)) = o;
  }
}

// ---------------- 256x256 8-phase GEMM (r4 skeleton, r6 staging) ----------
// LDS rows = 64 bf16 (8 x 16B chunks); chunk c of row r at LDS chunk
// (c ^ (r&7)); LDS linear + pre-swizzled global source (rule #21).
// LDS map (shorts): A buf0 @0, A buf1 @16384, B buf0 @32768, B buf1 @49152.
// Staging schedule per tile kt:
//   ph0 -> B(kt+1) rows 0-127,  ph1 -> B(kt+1) rows 128-255,
//   ph2 -> A(kt+1) rows 64-127 & 192-255 ("A-hi", consumed ph2),
//   ph3 -> A(kt+2) rows 0-63 & 128-191  ("A-lo", consumed ph0, 1.5 tiles ahead).
// Waits: vmcnt(6) at ph1-end (A-hi(kt) landed), vmcnt(4) at ph3-end
// (B(kt+1) + A-lo(kt+1) landed).

template<int PHASE1>
__global__ __launch_bounds__(512, 2) void gemm256(
    const unsigned short* __restrict__ A,
    const unsigned short* __restrict__ Bt,
    const float* __restrict__ bias,
    void* __restrict__ Out,
    int p0)
{
  constexpr int M  = 1024;
  constexpr int K  = PHASE1 ? 1024 : 4096;
  constexpr int Nd = PHASE1 ? 4096 : 1024;
  constexpr int TM = M / 256, TN = Nd / 256;
  constexpr int NT = K / 64;                 // 16 or 64 (even, >=4)

  const int cpx = gridDim.x >> 3;
  const int bid = (blockIdx.x & 7) * cpx + (blockIdx.x >> 3);
  const int tn = bid % TN;
  const int t2 = bid / TN;
  const int tm = t2 % TM;
  const int cp = t2 / TM;
  const int p  = p0 + cp, e = p & 7;
  const int m0 = tm * 256, n0 = tn * 256;

  const unsigned short* Ag = A  + (size_t)(PHASE1 ? p : cp) * M * K + (size_t)m0 * K;
  const unsigned short* Bg = Bt + (size_t)e * Nd * K + (size_t)n0 * K;
  const float*          bp = bias + (size_t)e * Nd;

  __shared__ __align__(16) unsigned short lds[65536];

  const int tid = threadIdx.x;
  const int w = tid >> 6, lane = tid & 63;
  const int wr = w >> 2, wc = w & 3;          // 2 x 4 waves; wave tile 128 x 64
  const int c15 = lane & 15, q = lane >> 4;

  // staging: per-thread row within a 64-row block + swizzled chunk (shorts)
  const int trow = (w << 3) + (lane >> 3);                 // 0..63
  const int scol = ((lane & 7) ^ (trow & 7)) << 3;
  const unsigned short* pA0 = Ag + (size_t)(trow       ) * K + scol;
  const unsigned short* pA1 = Ag + (size_t)(trow +  64) * K + scol;
  const unsigned short* pA2 = Ag + (size_t)(trow + 128) * K + scol;
  const unsigned short* pA3 = Ag + (size_t)(trow + 192) * K + scol;
  const unsigned short* pB0 = Bg + (size_t)(trow       ) * K + scol;
  const unsigned short* pB1 = Bg + (size_t)(trow +  64) * K + scol;
  const unsigned short* pB2 = Bg + (size_t)(trow + 128) * K + scol;
  const unsigned short* pB3 = Bg + (size_t)(trow + 192) * K + scol;
  const int wof = w << 9;                                  // LDS dest base (shorts)

  // frag-read per-thread constants (shorts)
  const int rA64 = (wr * 128 + c15) << 6;
  const int rB64 = (wc * 64  + c15) << 6;
  const int cx0 = ( q      ^ (c15 & 7)) << 3;              // kk=0 chunk
  const int cx1 = ((q ^ 4) ^ (c15 & 7)) << 3;              // kk=1 chunk

  // bias folded into accumulator init
  float bv[4];
  #pragma unroll
  for (int nf = 0; nf < 4; ++nf) bv[nf] = bp[n0 + wc * 64 + nf * 16 + c15];

  f32x4 acc[8][4];
  #pragma unroll
  for (int i = 0; i < 8; i++)
    #pragma unroll
    for (int j = 0; j < 4; j++) acc[i][j] = (f32x4)(bv[j]);

  // ---- prologue: tile0 (A+B) into buf0; A-lo(tile1) into buf1 ----
  glds16(pA0, lds + wof);
  glds16(pA1, lds + wof + 4096);
  glds16(pA2, lds + wof + 8192);
  glds16(pA3, lds + wof + 12288);
  glds16(pB0, lds + wof + 32768);
  glds16(pB1, lds + wof + 32768 + 4096);
  glds16(pB2, lds + wof + 32768 + 8192);
  glds16(pB3, lds + wof + 32768 + 12288);
  glds16(pA0 + 64, lds + wof + 16384);            // A-lo(1): rows 0-63
  glds16(pA2 + 64, lds + wof + 16384 + 8192);     // A-lo(1): rows 128-191
  asm volatile("s_waitcnt vmcnt(2)" ::: "memory");
  BAR();

  short8 af[4][2], bf0[2][2], bf1[2][2];

  // One K-tile. SB1: stage B(kt+1)+A-hi(kt+1). SA2: stage A-lo(kt+2).
  // W1/W3: vmcnt values at ph1-end / ph3-end (-1 = none).
#define TILE_BODY(CB, SB1, SA2, W1, W3) do{                                     \
    constexpr int AB  = (CB) * 16384;                                           \
    constexpr int BB  = 32768 + (CB) * 16384;                                   \
    constexpr int ABn = ((CB) ^ 1) * 16384;                                     \
    constexpr int BBn = 32768 + (((CB) ^ 1) * 16384);                           \
    constexpr int O1  = (CB) ? 128 : 64;                                        \
    constexpr int O2  = (CB) ? 192 : 128;                                       \
    /* ph0: q(m0,n0); reads af<-A-lo, bf0; stage B(kt+1) rows 0-127 */          \
    _Pragma("unroll")                                                           \
    for (int mf = 0; mf < 4; ++mf){                                             \
      af[mf][0] = *(const short8*)(lds + AB + rA64 + mf * 1024 + cx0);          \
      af[mf][1] = *(const short8*)(lds + AB + rA64 + mf * 1024 + cx1);          \
    }                                                                           \
    _Pragma("unroll")                                                           \
    for (int nf = 0; nf < 2; ++nf){                                             \
      bf0[nf][0] = *(const short8*)(lds + BB + rB64 + nf * 1024 + cx0);         \
      bf0[nf][1] = *(const short8*)(lds + BB + rB64 + nf * 1024 + cx1);         \
    }                                                                           \
    if (SB1){ glds16(pB0 + O1, lds + BBn + wof);                                \
              glds16(pB1 + O1, lds + BBn + 4096 + wof); }                       \
    BAR();                                                                      \
    __builtin_amdgcn_s_setprio(1);                                              \
    _Pragma("unroll")                                                           \
    for (int mf = 0; mf < 4; ++mf)                                              \
      _Pragma("unroll")                                                         \
      for (int nf = 0; nf < 2; ++nf){                                           \
        acc[mf][nf] = __builtin_amdgcn_mfma_f32_16x16x32_bf16(af[mf][0], bf0[nf][0], acc[mf][nf], 0, 0, 0); \
        acc[mf][nf] = __builtin_amdgcn_mfma_f32_16x16x32_bf16(af[mf][1], bf0[nf][1], acc[mf][nf], 0, 0, 0); \
      }                                                                         \
    __builtin_amdgcn_s_setprio(0);                                              \
    BAR();                                                                      \
    /* ph1: q(m0,n1); reads bf1; stage B(kt+1) rows 128-255; W1 */              \
    _Pragma("unroll")                                                           \
    for (int nf = 0; nf < 2; ++nf){                                             \
      bf1[nf][0] = *(const short8*)(lds + BB + rB64 + 2048 + nf * 1024 + cx0);  \
      bf1[nf][1] = *(const short8*)(lds + BB + rB64 + 2048 + nf * 1024 + cx1);  \
    }                                                                           \
    if (SB1){ glds16(pB2 + O1, lds + BBn + 8192 + wof);                         \
              glds16(pB3 + O1, lds + BBn + 12288 + wof); }                      \
    BAR();                                                                      \
    __builtin_amdgcn_s_setprio(1);                                              \
    _Pragma("unroll")                                                           \
    for (int mf = 0; mf < 4; ++mf)                                              \
      _Pragma("unroll")                                                         \
      for (int nf = 0; nf < 2; ++nf){                                           \
        acc[mf][2+nf] = __builtin_amdgcn_mfma_f32_16x16x32_bf16(af[mf][0], bf1[nf][0], acc[mf][2+nf], 0, 0, 0); \
        acc[mf][2+nf] = __builtin_amdgcn_mfma_f32_16x16x32_bf16(af[mf][1], bf1[nf][1], acc[mf][2+nf], 0, 0, 0); \
      }                                                                         \
    __builtin_amdgcn_s_setprio(0);                                              \
    if ((W1) >= 0) VMW(W1);                                                     \
    BAR();                                                                      \
    /* ph2: q(m1,n1); reads af<-A-hi; stage A-hi(kt+1) */                       \
    _Pragma("unroll")                                                           \
    for (int mf = 0; mf < 4; ++mf){                                             \
      af[mf][0] = *(const short8*)(lds + AB + rA64 + 4096 + mf * 1024 + cx0);   \
      af[mf][1] = *(const short8*)(lds + AB + rA64 + 4096 + mf * 1024 + cx1);   \
    }                                                                           \
    if (SB1){ glds16(pA1 + O1, lds + ABn + 4096 + wof);                         \
              glds16(pA3 + O1, lds + ABn + 12288 + wof); }                      \
    BAR();                                                                      \
    __builtin_amdgcn_s_setprio(1);                                              \
    _Pragma("unroll")                                                           \
    for (int mf = 0; mf < 4; ++mf)                                              \
      _Pragma("unroll")                                                         \
      for (int nf = 0; nf < 2; ++nf){                                           \
        acc[4+mf][2+nf] = __builtin_amdgcn_mfma_f32_16x16x32_bf16(af[mf][0], bf1[nf][0], acc[4+mf][2+nf], 0, 0, 0); \
        acc[4+mf][2+nf] = __builtin_amdgcn_mfma_f32_16x16x32_bf16(af[mf][1], bf1[nf][1], acc[4+mf][2+nf], 0, 0, 0); \
      }                                                                         \
    __builtin_amdgcn_s_setprio(0);                                              \
    BAR();                                                                      \
    /* ph3: q(m1,n0) reg-only; stage A-lo(kt+2) into CURRENT A buf rows        \
       0-63 & 128-191 (their last reads were ph0; >=2 barriers ago); W3 */      \
    if (SA2){ glds16(pA0 + O2, lds + AB + wof);                                 \
              glds16(pA2 + O2, lds + AB + 8192 + wof); }                        \
    BAR();                                                                      \
    __builtin_amdgcn_s_setprio(1);                                              \
    _Pragma("unroll")                                                           \
    for (int mf = 0; mf < 4; ++mf)                                              \
      _Pragma("unroll")                                                         \
      for (int nf = 0; nf < 2; ++nf){                                           \
        acc[4+mf][nf] = __builtin_amdgcn_mfma_f32_16x16x32_bf16(af[mf][0], bf0[nf][0], acc[4+mf][nf], 0, 0, 0); \
        acc[4+mf][nf] = __builtin_amdgcn_mfma_f32_16x16x32_bf16(af[mf][1], bf0[nf][1], acc[4+mf][nf], 0, 0, 0); \
      }                                                                         \
    __builtin_amdgcn_s_setprio(0);                                              \
    if ((W3) >= 0) VMW(W3);                                                     \
    BAR();                                                                      \
  }while(0)

  for (int kt2 = 0; kt2 < NT - 2; kt2 += 2){
    TILE_BODY(0, 1, 1, 6, 4);
    TILE_BODY(1, 1, 1, 6, 4);
    pA0 += 128; pA1 += 128; pA2 += 128; pA3 += 128;
    pB0 += 128; pB1 += 128; pB2 += 128; pB3 += 128;
  }
  TILE_BODY(0, 1, 0, 6, 2);    // kt = NT-2: stage tile NT-1 (no A-lo(kt+2))
  TILE_BODY(1, 0, 0, 0, -1);   // kt = NT-1: compute only
#undef TILE_BODY

  // ---- epilogue: C/D layout col = lane&15, row = (lane>>4)*4 + r ----
  #pragma unroll
  for (int mf = 0; mf < 8; ++mf){
    const int row = m0 + wr * 128 + mf * 16 + q * 4;
    #pragma unroll
    for (int nf = 0; nf < 4; ++nf){
      const int col = n0 + wc * 64 + nf * 16 + c15;
      #pragma unroll
      for (int r = 0; r < 4; ++r){
        float v = acc[mf][nf][r];
        if constexpr (PHASE1){
          ((unsigned short*)Out)[(size_t)cp * M * Nd + (size_t)(row + r) * Nd + col] = f2b(gelu_fast(v));
        } else {
          ((float*)Out)[(size_t)p * M * Nd + (size_t)(row + r) * Nd + col] = v;
        }
      }
    }
  }
}

// ---------------- launch ----------------

extern "C" void kernel_launch(void* const* d_in, const int* in_sizes, int n_in,
                              void* d_out, int out_size, void* d_ws, size_t ws_size,
                              hipStream_t stream){
  const float* x  = (const float*)d_in[0];
  const float* w1 = (const float*)d_in[1];
  const float* b1 = (const float*)d_in[2];
  const float* w2 = (const float*)d_in[3];
  const float* b2 = (const float*)d_in[4];
  float* out = (float*)d_out;

  unsigned short* xb  = (unsigned short*)d_ws;
  unsigned short* w1t = (unsigned short*)((char*)d_ws + ((size_t)64  << 20));
  unsigned short* w2t = (unsigned short*)((char*)d_ws + ((size_t)128 << 20));
  unsigned short* hb  = (unsigned short*)((char*)d_ws + ((size_t)192 << 20));

  size_t avail = ws_size > ((size_t)192 << 20) ? ws_size - ((size_t)192 << 20) : 0;
  int ppc = (int)(avail / ((size_t)8 << 20));
  if (ppc > 32) ppc = 32;
  if (ppc < 1) return;

  cvt_x_kernel<<<2048, 256, 0, stream>>>(x, xb, 8 * 1024 * 1024);
  transpose_cvt<<<dim3(64, 16, 8), 256, 0, stream>>>(w1, w1t, 1024, 4096);
  transpose_cvt<<<dim3(16, 64, 8), 256, 0, stream>>>(w2, w2t, 4096, 1024);

  for (int p0 = 0; p0 < 32; p0 += ppc){
    int np = (32 - p0 < ppc) ? (32 - p0) : ppc;
    // GEMM1: h = gelu(xb @ w1t^T + b1)   [M=1024, K=1024, Nd=4096]
    gemm256<1><<<dim3(np * 4 * 16), 512, 0, stream>>>(xb, w1t, b1, hb, p0);
    // GEMM2: out = h @ w2t^T + b2        [M=1024, K=4096, Nd=1024]
    gemm256<0><<<dim3(np * 4 * 4),  512, 0, stream>>>(hb, w2t, b2, out, p0);
  }
}